// Round 4
// baseline (364.883 us; speedup 1.0000x reference)
//
#include <hip/hip_runtime.h>

// Decoder scan: B=256 batch, T=128, M=64, P=64, 127 sequential steps.
// One block per batch element (256 blocks = 256 CUs), 512 threads (8 waves).
// 3 barriers/step. dproj + softmax-denom + ys accumulated via LDS float
// atomics (ds_add_f32); exp(e_t) passed e->f through registers (v_readlane).
// Wd, enc, Ue, x all in per-lane registers.

#define Bn 256
#define Tn 128
#define Mn 64
#define Pn 64
#define NTH 512
#define NW 8
#define UST 68   // padded stride (floats) for enc_s / Ud_s (init staging)
#define K2C 2.885390081777927f  // 2 * log2(e)

typedef float f32x2 __attribute__((ext_vector_type(2)));

__device__ __forceinline__ float fexp(float x) {   // e^x
    return __builtin_amdgcn_exp2f(x * 1.44269504088896341f);
}
__device__ __forceinline__ float fexp2(float x) { return __builtin_amdgcn_exp2f(x); }
__device__ __forceinline__ float frcp(float x) { return __builtin_amdgcn_rcpf(x); }
__device__ __forceinline__ float fsig(float x) { return frcp(1.0f + fexp(-x)); }
__device__ __forceinline__ float ftanh(float x) { return 1.0f - 2.0f * frcp(1.0f + fexp(2.0f * x)); }

template <int CTRL>
__device__ __forceinline__ float dppmov(float x) {
    // invalid source lanes contribute old=0 (safe for additive reductions)
    return __int_as_float(__builtin_amdgcn_update_dpp(
        0, __float_as_int(x), CTRL, 0xf, 0xf, false));
}
__device__ __forceinline__ float rdlane(float x, int l) {
    return __int_as_float(__builtin_amdgcn_readlane(__float_as_int(x), l));
}
// 64-lane sum; total lands in lane 63 (NOT broadcast)
__device__ __forceinline__ float wavesum63(float x) {
    x += dppmov<0x111>(x);  // row_shr:1
    x += dppmov<0x112>(x);  // row_shr:2
    x += dppmov<0x114>(x);  // row_shr:4
    x += dppmov<0x118>(x);  // row_shr:8
    x += dppmov<0x142>(x);  // row_bcast:15
    x += dppmov<0x143>(x);  // row_bcast:31
    return x;
}

// LDS layout (floats):
#define OFF_ENC   0        // 128*68 = 8704 (init only)
#define OFF_UD    8704     // 64*68  = 4352 (init only)
#define OFF_PRE   13056    // 256 (init only)
#define OFF_DPROJ 13312    // 64   (16B aligned)
#define OFF_DEN   13376    // 2
#define OFF_YS    13378    // 2
#define OFF_CTXP  13380    // 512
#define SMEM_FLOATS 13892  // 55.6 KB

__global__ __launch_bounds__(NTH, 1)
void decoder_kernel(const float* __restrict__ data, const float* __restrict__ enc,
                    const float* __restrict__ h0, const float* __restrict__ s0,
                    const float* __restrict__ W_dense, const float* __restrict__ b_dense,
                    const float* __restrict__ Wk, const float* __restrict__ Uk,
                    const float* __restrict__ bk,
                    const float* __restrict__ Wd, const float* __restrict__ bWd,
                    const float* __restrict__ Ud, const float* __restrict__ bUd,
                    const float* __restrict__ vd, const float* __restrict__ bvd,
                    const float* __restrict__ Wvb, const float* __restrict__ bvb,
                    const float* __restrict__ Wb, const float* __restrict__ bWb,
                    float* __restrict__ out)
{
    extern __shared__ float smem[];
    float* enc_s   = smem + OFF_ENC;
    float* Ud_s    = smem + OFF_UD;
    float* pre_s   = smem + OFF_PRE;
    float* dproj_s = smem + OFF_DPROJ;
    float* den_s   = smem + OFF_DEN;
    float* ys_s    = smem + OFF_YS;
    float* ctxp    = smem + OFF_CTXP;

    const int b    = blockIdx.x;
    const int tid  = threadIdx.x;
    const int lane = tid & 63;
    const int wv   = tid >> 6;

    // ---- init: stage enc (stride 68), Ud (stride 68); pre = h0@Uk+bk ----
    {
        const float* encg = enc + (size_t)b * Tn * Mn;
        #pragma unroll
        for (int i = 0; i < 4; i++) {
            int flat = (i * NTH + tid) * 4;          // 0..8188
            int t = flat >> 6, m = flat & 63;
            *(float4*)(enc_s + t * UST + m) = *(const float4*)(encg + flat);
        }
        #pragma unroll
        for (int i = 0; i < 2; i++) {
            int flat = (i * NTH + tid) * 4;          // 0..4092
            int k = flat >> 6, n = flat & 63;
            *(float4*)(Ud_s + k * UST + n) = *(const float4*)(Ud + flat);
        }
        if (tid < 4 * Pn) {
            float s = bk[tid];
            const float* h0b = h0 + b * Pn;
            #pragma unroll
            for (int k = 0; k < Pn; k++) s = fmaf(h0b[k], Uk[k * 4 * Pn + tid], s);
            pre_s[tid] = s;
        }
        if (tid < 64) dproj_s[tid] = K2C * bWd[tid];
        if (tid < 2) { den_s[tid] = 0.0f; ys_s[tid] = 0.0f; }
    }
    __syncthreads();

    // ---- Ue slice in registers: ue = K2 * (enc[t_e] @ Ud[:,m0+j] + bUd) ----
    const int t_e = tid >> 2, q_e = tid & 3, m0 = q_e * 16;
    f32x2 ue2[8];
    {
        float acc[16];
        #pragma unroll
        for (int j = 0; j < 16; j++) acc[j] = bUd[m0 + j];
        for (int k = 0; k < Mn; k++) {
            float a = enc_s[t_e * UST + k];
            const float4* ud = (const float4*)(Ud_s + k * UST + m0);
            #pragma unroll
            for (int j4 = 0; j4 < 4; j4++) {
                float4 u = ud[j4];
                acc[4 * j4 + 0] = fmaf(a, u.x, acc[4 * j4 + 0]);
                acc[4 * j4 + 1] = fmaf(a, u.y, acc[4 * j4 + 1]);
                acc[4 * j4 + 2] = fmaf(a, u.z, acc[4 * j4 + 2]);
                acc[4 * j4 + 3] = fmaf(a, u.w, acc[4 * j4 + 3]);
            }
        }
        #pragma unroll
        for (int j = 0; j < 8; j++) {
            ue2[j].x = K2C * acc[2 * j];
            ue2[j].y = K2C * acc[2 * j + 1];
        }
    }

    // ---- per-lane loop-invariant registers ----
    float enc_r[16], wd_r[16];
    #pragma unroll
    for (int j = 0; j < 16; j++) {
        enc_r[j] = enc_s[(16 * wv + j) * UST + lane];   // wave's 16 enc rows
        wd_r[j]  = K2C * Wd[(16 * wv + j) * Mn + lane]; // wave's 16 Wd rows, pre-scaled
    }
    const float W0  = W_dense[0];
    const float bd  = b_dense[0];
    const float Wde = W_dense[1 + lane];
    const float wk_i = Wk[lane], wk_f = Wk[64 + lane],
                wk_g = Wk[128 + lane], wk_o = Wk[192 + lane];
    const float s0v   = s0[b * Pn + lane];
    const float bvd0  = bvd[0];
    const float bwd_pre = K2C * bWd[lane];             // for wave0 dproj reinit
    f32x2 vd2[8];
    float sumvd16 = 0.0f;
    #pragma unroll
    for (int j = 0; j < 8; j++) {
        float va = vd[m0 + 2 * j], vb = vd[m0 + 2 * j + 1];
        vd2[j].x = -2.0f * va; vd2[j].y = -2.0f * vb;
        sumvd16 += va + vb;
    }
    const float pre_i = pre_s[lane];
    const float pre_f = pre_s[64 + lane];
    const float pre_g = pre_s[128 + lane];
    const float pre_o = pre_s[192 + lane];
    const bool hv_sel = (wv < 4);
    const int  base16 = (wv & 3) * 16;
    // x row in registers (broadcast later via v_readlane)
    const float* xb = data + (size_t)b * (Tn - 1);
    const float x_lo = xb[lane];                          // lane 0..63
    const float x_hi = (lane < 63) ? xb[64 + lane] : 0.0f; // 64..126

    float h = 0.0f, c = 0.0f;

    for (int st = 0; st < Tn - 1; ++st) {
        const int par = st & 1, nxt = par ^ 1;

        // phase a: y = x[st]*W0 + ys + bd   (ys = full ctx.Wde dot via atomics)
        float ysv = ys_s[par];                         // uniform broadcast read
        float xs = (st < 64) ? rdlane(x_lo, st) : rdlane(x_hi, st - 64);
        float y = fmaf(xs, W0, ysv + bd);

        // phase b: LSTM gates (state resets to h0,s0; pre = h0@Uk+bk)
        float zi = fmaf(y, wk_i, pre_i);
        float zf = fmaf(y, wk_f, pre_f);
        float zg = fmaf(y, wk_g, pre_g);
        float zo = fmaf(y, wk_o, pre_o);
        c = fsig(zf) * s0v + fsig(zi) * ftanh(zg);
        h = fsig(zo) * ftanh(c);

        // phase c: dproj[lane] += sum_{j<16} hc[16wv'+j] * K2*Wd[..][lane]
        {
            float hv = hv_sel ? h : c;
            float p0 = 0.0f, p1 = 0.0f, p2 = 0.0f, p3 = 0.0f;
            #pragma unroll
            for (int j = 0; j < 4; j++) {
                p0 = fmaf(rdlane(hv, base16 + j),      wd_r[j],      p0);
                p1 = fmaf(rdlane(hv, base16 + 4 + j),  wd_r[4 + j],  p1);
                p2 = fmaf(rdlane(hv, base16 + 8 + j),  wd_r[8 + j],  p2);
                p3 = fmaf(rdlane(hv, base16 + 12 + j), wd_r[12 + j], p3);
            }
            atomicAdd(&dproj_s[lane], (p0 + p1) + (p2 + p3));
        }
        __syncthreads();  // B1: dproj complete

        // phase e: e[t] = sum_m vd*tanh(dproj+Ue); ex = exp(e) kept in regs;
        //          denom accumulated via atomic
        float ex;
        {
            const float4* dp4 = (const float4*)(dproj_s + m0);
            float4 d0 = dp4[0], d1 = dp4[1], d2 = dp4[2], d3 = dp4[3];
            f32x2 accA; accA.x = sumvd16; accA.y = 0.0f;
            f32x2 accB; accB.x = 0.0f;    accB.y = 0.0f;
            f32x2 s, r;
            s.x = d0.x + ue2[0].x; s.y = d0.y + ue2[0].y;
            r.x = frcp(1.0f + fexp2(s.x)); r.y = frcp(1.0f + fexp2(s.y));
            accA += vd2[0] * r;
            s.x = d0.z + ue2[1].x; s.y = d0.w + ue2[1].y;
            r.x = frcp(1.0f + fexp2(s.x)); r.y = frcp(1.0f + fexp2(s.y));
            accB += vd2[1] * r;
            s.x = d1.x + ue2[2].x; s.y = d1.y + ue2[2].y;
            r.x = frcp(1.0f + fexp2(s.x)); r.y = frcp(1.0f + fexp2(s.y));
            accA += vd2[2] * r;
            s.x = d1.z + ue2[3].x; s.y = d1.w + ue2[3].y;
            r.x = frcp(1.0f + fexp2(s.x)); r.y = frcp(1.0f + fexp2(s.y));
            accB += vd2[3] * r;
            s.x = d2.x + ue2[4].x; s.y = d2.y + ue2[4].y;
            r.x = frcp(1.0f + fexp2(s.x)); r.y = frcp(1.0f + fexp2(s.y));
            accA += vd2[4] * r;
            s.x = d2.z + ue2[5].x; s.y = d2.w + ue2[5].y;
            r.x = frcp(1.0f + fexp2(s.x)); r.y = frcp(1.0f + fexp2(s.y));
            accB += vd2[5] * r;
            s.x = d3.x + ue2[6].x; s.y = d3.y + ue2[6].y;
            r.x = frcp(1.0f + fexp2(s.x)); r.y = frcp(1.0f + fexp2(s.y));
            accA += vd2[6] * r;
            s.x = d3.z + ue2[7].x; s.y = d3.w + ue2[7].y;
            r.x = frcp(1.0f + fexp2(s.x)); r.y = frcp(1.0f + fexp2(s.y));
            accB += vd2[7] * r;
            f32x2 accT = accA + accB;
            float acc = accT.x + accT.y;
            acc += dppmov<0x111>(acc);
            acc += dppmov<0x112>(acc);   // q==3 lanes hold full e[t]
            ex = fexp(acc + bvd0);       // valid at q==3 lanes
            float exm = (q_e == 3) ? ex : 0.0f;
            float dsum = wavesum63(exm); // wave's 16-ex sum at lane 63
            if (lane == 63) atomicAdd(&den_s[par], dsum);
        }
        __syncthreads();  // B2: denom complete

        // phase f: ctx partials from own-register ex; ys via atomic; reinit
        {
            float invS = frcp(den_s[par]);             // uniform broadcast read
            float p0 = 0.0f, p1 = 0.0f, p2 = 0.0f, p3 = 0.0f;
            #pragma unroll
            for (int j = 0; j < 4; j++) {
                p0 = fmaf(rdlane(ex, 4 * j + 3),        enc_r[j],      p0);
                p1 = fmaf(rdlane(ex, 4 * (j + 4) + 3),  enc_r[4 + j],  p1);
                p2 = fmaf(rdlane(ex, 4 * (j + 8) + 3),  enc_r[8 + j],  p2);
                p3 = fmaf(rdlane(ex, 4 * (j + 12) + 3), enc_r[12 + j], p3);
            }
            float ctxv = ((p0 + p1) + (p2 + p3)) * invS;
            float yw = wavesum63(ctxv * Wde);
            if (lane == 63) atomicAdd(&ys_s[nxt], yw);
            if (tid == 0) ys_s[par] = 0.0f;
            if (tid == 1) den_s[nxt] = 0.0f;
            if (wv == 0) dproj_s[lane] = bwd_pre;      // reinit for next step
            if (st == Tn - 2) ctxp[wv * 64 + lane] = ctxv;
        }
        __syncthreads();  // B3
    }

    // ---- epilogue: out[b][p] = ((concat(h,ctx) @ Wvb + bvb) * Wb[p]) + bWb[p] ----
    if (wv == 0) {
        float ctxm = 0.0f;
        #pragma unroll
        for (int w = 0; w < NW; w++) ctxm += ctxp[w * 64 + lane];
        float part = h * Wvb[lane] + ctxm * Wvb[64 + lane];
        float v = rdlane(wavesum63(part), 63) + bvb[0];
        out[(size_t)b * Pn + lane] = fmaf(v, Wb[lane], bWb[lane]);
    }
}

extern "C" void kernel_launch(void* const* d_in, const int* in_sizes, int n_in,
                              void* d_out, int out_size, void* d_ws, size_t ws_size,
                              hipStream_t stream) {
    const float* data    = (const float*)d_in[0];
    const float* enc     = (const float*)d_in[1];
    const float* h0      = (const float*)d_in[2];
    const float* s0      = (const float*)d_in[3];
    const float* W_dense = (const float*)d_in[4];
    const float* b_dense = (const float*)d_in[5];
    const float* Wk      = (const float*)d_in[6];
    const float* Uk      = (const float*)d_in[7];
    const float* bk      = (const float*)d_in[8];
    const float* Wd      = (const float*)d_in[9];
    const float* bWd     = (const float*)d_in[10];
    const float* Ud      = (const float*)d_in[11];
    const float* bUd     = (const float*)d_in[12];
    const float* vd      = (const float*)d_in[13];
    const float* bvd     = (const float*)d_in[14];
    const float* Wvb     = (const float*)d_in[15];
    const float* bvb     = (const float*)d_in[16];
    const float* Wb      = (const float*)d_in[17];
    const float* bWb     = (const float*)d_in[18];

    decoder_kernel<<<Bn, NTH, SMEM_FLOATS * sizeof(float), stream>>>(
        data, enc, h0, s0, W_dense, b_dense, Wk, Uk, bk,
        Wd, bWd, Ud, bUd, vd, bvd, Wvb, bvb, Wb, bWb, (float*)d_out);
}

// Round 5
// 328.303 us; speedup vs baseline: 1.1114x; 1.1114x over previous
//
#include <hip/hip_runtime.h>

// Decoder scan: B=256 batch, T=128, M=64, P=64, 127 sequential steps.
// One block per batch element (256 blocks = 256 CUs), 256 threads (4 waves,
// 1 wave/SIMD -> no issue contention on the serial critical path).
// 4 barriers/step; dpart->dproj reduce via LDS (no atomics).
// Wd, enc, Ue, x, vd all in per-lane registers; cross-lane via DPP/readlane.

#define Bn 256
#define Tn 128
#define Mn 64
#define Pn 64
#define NTH 256
#define NW 4
#define UST 68   // padded stride (floats) for enc_s / Ud_s (init staging)
#define DPST 72  // padded stride for dpart
#define K2C 2.885390081777927f  // 2 * log2(e)

typedef float f32x2 __attribute__((ext_vector_type(2)));

__device__ __forceinline__ float fexp(float x) {   // e^x
    return __builtin_amdgcn_exp2f(x * 1.44269504088896341f);
}
__device__ __forceinline__ float fexp2(float x) { return __builtin_amdgcn_exp2f(x); }
__device__ __forceinline__ float frcp(float x) { return __builtin_amdgcn_rcpf(x); }
__device__ __forceinline__ float fsig(float x) { return frcp(1.0f + fexp(-x)); }
__device__ __forceinline__ float ftanh(float x) { return 1.0f - 2.0f * frcp(1.0f + fexp(2.0f * x)); }

template <int CTRL>
__device__ __forceinline__ float dppmov(float x) {
    // invalid source lanes contribute old=0 (safe for additive reductions)
    return __int_as_float(__builtin_amdgcn_update_dpp(
        0, __float_as_int(x), CTRL, 0xf, 0xf, false));
}
__device__ __forceinline__ float rdlane(float x, int l) {
    return __int_as_float(__builtin_amdgcn_readlane(__float_as_int(x), l));
}
// 64-lane sum; total lands in lane 63 (NOT broadcast)
__device__ __forceinline__ float wavesum63(float x) {
    x += dppmov<0x111>(x);  // row_shr:1
    x += dppmov<0x112>(x);  // row_shr:2
    x += dppmov<0x114>(x);  // row_shr:4
    x += dppmov<0x118>(x);  // row_shr:8
    x += dppmov<0x142>(x);  // row_bcast:15
    x += dppmov<0x143>(x);  // row_bcast:31
    return x;
}

// LDS layout (floats):
#define OFF_ENC   0        // 128*68 = 8704 (init only)
#define OFF_UD    8704     // 64*68  = 4352 (init only)
#define OFF_PRE   13056    // 256 (init only)
#define OFF_DPART 13312    // 4*72 = 288
#define OFF_DPROJ 13600    // 64  (16B aligned)
#define OFF_ES    13664    // 128
#define OFF_CTXP  13792    // 256
#define OFF_YS    14048    // 4
#define SMEM_FLOATS 14056  // 56.2 KB

__global__ __launch_bounds__(NTH, 1)
void decoder_kernel(const float* __restrict__ data, const float* __restrict__ enc,
                    const float* __restrict__ h0, const float* __restrict__ s0,
                    const float* __restrict__ W_dense, const float* __restrict__ b_dense,
                    const float* __restrict__ Wk, const float* __restrict__ Uk,
                    const float* __restrict__ bk,
                    const float* __restrict__ Wd, const float* __restrict__ bWd,
                    const float* __restrict__ Ud, const float* __restrict__ bUd,
                    const float* __restrict__ vd, const float* __restrict__ bvd,
                    const float* __restrict__ Wvb, const float* __restrict__ bvb,
                    const float* __restrict__ Wb, const float* __restrict__ bWb,
                    float* __restrict__ out)
{
    extern __shared__ float smem[];
    float* enc_s   = smem + OFF_ENC;
    float* Ud_s    = smem + OFF_UD;
    float* pre_s   = smem + OFF_PRE;
    float* dpart   = smem + OFF_DPART;
    float* dproj_s = smem + OFF_DPROJ;
    float* e_s     = smem + OFF_ES;
    float* ctxp    = smem + OFF_CTXP;
    float* ys_s    = smem + OFF_YS;

    const int b    = blockIdx.x;
    const int tid  = threadIdx.x;
    const int lane = tid & 63;
    const int wv   = tid >> 6;          // 0..3

    // ---- init: stage enc (stride 68), Ud (stride 68); pre = h0@Uk+bk ----
    {
        const float* encg = enc + (size_t)b * Tn * Mn;
        #pragma unroll
        for (int i = 0; i < 8; i++) {
            int flat = (i * NTH + tid) * 4;          // 0..8188
            int t = flat >> 6, m = flat & 63;
            *(float4*)(enc_s + t * UST + m) = *(const float4*)(encg + flat);
        }
        #pragma unroll
        for (int i = 0; i < 4; i++) {
            int flat = (i * NTH + tid) * 4;          // 0..4092
            int k = flat >> 6, n = flat & 63;
            *(float4*)(Ud_s + k * UST + n) = *(const float4*)(Ud + flat);
        }
        {   // tid covers 0..255 == 4P exactly
            float s = bk[tid];
            const float* h0b = h0 + b * Pn;
            #pragma unroll
            for (int k = 0; k < Pn; k++) s = fmaf(h0b[k], Uk[k * 4 * Pn + tid], s);
            pre_s[tid] = s;
        }
        if (tid < NW) ys_s[tid] = 0.0f;
    }
    __syncthreads();

    // ---- Ue slice in registers: ue = K2*(enc[t_e] @ Ud[:, m0..m0+31] + bUd) ----
    const int t_e = tid >> 1, q_e = tid & 1, m0 = q_e * 32;
    f32x2 ue2[16];
    {
        float acc[32];
        #pragma unroll
        for (int j = 0; j < 32; j++) acc[j] = bUd[m0 + j];
        for (int k = 0; k < Mn; k++) {
            float a = enc_s[t_e * UST + k];
            const float4* ud = (const float4*)(Ud_s + k * UST + m0);
            #pragma unroll
            for (int j4 = 0; j4 < 8; j4++) {
                float4 u = ud[j4];
                acc[4 * j4 + 0] = fmaf(a, u.x, acc[4 * j4 + 0]);
                acc[4 * j4 + 1] = fmaf(a, u.y, acc[4 * j4 + 1]);
                acc[4 * j4 + 2] = fmaf(a, u.z, acc[4 * j4 + 2]);
                acc[4 * j4 + 3] = fmaf(a, u.w, acc[4 * j4 + 3]);
            }
        }
        #pragma unroll
        for (int j = 0; j < 16; j++) {
            ue2[j].x = K2C * acc[2 * j];
            ue2[j].y = K2C * acc[2 * j + 1];
        }
    }

    // ---- per-lane loop-invariant registers ----
    float enc_r[32], wd_r[32];
    #pragma unroll
    for (int j = 0; j < 32; j++) {
        enc_r[j] = enc_s[(32 * wv + j) * UST + lane];   // wave's 32 enc rows
        wd_r[j]  = K2C * Wd[(32 * wv + j) * Mn + lane]; // wave's 32 Wd rows, pre-scaled
    }
    const float W0  = W_dense[0];
    const float bd  = b_dense[0];
    const float Wde = W_dense[1 + lane];
    const float wk_i = Wk[lane], wk_f = Wk[64 + lane],
                wk_g = Wk[128 + lane], wk_o = Wk[192 + lane];
    const float s0v   = s0[b * Pn + lane];
    const float bvd0  = bvd[0];
    const float bwd_d = K2C * bWd[tid >> 2];           // phase-d writer bias
    f32x2 vd2[16];
    float sumvd32 = 0.0f;
    #pragma unroll
    for (int j = 0; j < 16; j++) {
        float va = vd[m0 + 2 * j], vb = vd[m0 + 2 * j + 1];
        vd2[j].x = -2.0f * va; vd2[j].y = -2.0f * vb;
        sumvd32 += va + vb;
    }
    const float pre_i = pre_s[lane];
    const float pre_f = pre_s[64 + lane];
    const float pre_g = pre_s[128 + lane];
    const float pre_o = pre_s[192 + lane];
    const bool hv_sel = (wv < 2);
    const int  base32 = (wv & 1) * 32;
    const int  m_d = tid >> 2, w_d = tid & 3;          // phase-d mapping
    // x row in registers (broadcast later via v_readlane)
    const float* xb = data + (size_t)b * (Tn - 1);
    const float x_lo = xb[lane];                           // 0..63
    const float x_hi = (lane < 63) ? xb[64 + lane] : 0.0f; // 64..126

    float h = 0.0f, c = 0.0f;

    for (int st = 0; st < Tn - 1; ++st) {
        // phase a: y = x[st]*W0 + sum_w ys[w] + bd
        float yv = ys_s[lane & 3];
        yv += dppmov<0x111>(yv);
        yv += dppmov<0x112>(yv);            // lane 3 holds sum of 4
        float xs = (st < 64) ? rdlane(x_lo, st) : rdlane(x_hi, st - 64);
        float y = fmaf(xs, W0, rdlane(yv, 3) + bd);

        // phase b: LSTM gates (state resets to h0,s0; pre = h0@Uk+bk)
        float zi = fmaf(y, wk_i, pre_i);
        float zf = fmaf(y, wk_f, pre_f);
        float zg = fmaf(y, wk_g, pre_g);
        float zo = fmaf(y, wk_o, pre_o);
        c = fsig(zf) * s0v + fsig(zi) * ftanh(zg);
        h = fsig(zo) * ftanh(c);

        // phase c: dpart[wv][m] = sum_{j<32} hc[32wv+j] * K2*Wd[32wv+j][m]
        {
            float hv = hv_sel ? h : c;
            float p0 = 0.0f, p1 = 0.0f, p2 = 0.0f, p3 = 0.0f;
            #pragma unroll
            for (int j = 0; j < 8; j++) {
                p0 = fmaf(rdlane(hv, base32 + j),      wd_r[j],      p0);
                p1 = fmaf(rdlane(hv, base32 + 8 + j),  wd_r[8 + j],  p1);
                p2 = fmaf(rdlane(hv, base32 + 16 + j), wd_r[16 + j], p2);
                p3 = fmaf(rdlane(hv, base32 + 24 + j), wd_r[24 + j], p3);
            }
            dpart[wv * DPST + lane] = (p0 + p1) + (p2 + p3);
        }
        __syncthreads();  // B1: dpart ready

        // phase d: thread (m_d, w_d) reduces 4 partials -> dproj[m_d]
        {
            float v = dpart[w_d * DPST + m_d];
            v += dppmov<0x111>(v);
            v += dppmov<0x112>(v);          // (lane&3)==3 holds sum over w
            if ((lane & 3) == 3) dproj_s[m_d] = v + bwd_d;
        }
        __syncthreads();  // B2: dproj ready

        // phase e: e[t] = sum_m vd*tanh(dproj+Ue); store exp(e) (|e|<~3, safe)
        float ex;
        {
            float4 d[8];
            const float4* dp4 = (const float4*)(dproj_s + m0);
            #pragma unroll
            for (int i = 0; i < 8; i++) d[i] = dp4[i];
            f32x2 accA; accA.x = sumvd32; accA.y = 0.0f;
            f32x2 accB; accB.x = 0.0f;    accB.y = 0.0f;
            #pragma unroll
            for (int i = 0; i < 8; i++) {
                f32x2 sA, rA, sB, rB;
                sA.x = d[i].x + ue2[2 * i].x;     sA.y = d[i].y + ue2[2 * i].y;
                rA.x = frcp(1.0f + fexp2(sA.x));  rA.y = frcp(1.0f + fexp2(sA.y));
                accA += vd2[2 * i] * rA;
                sB.x = d[i].z + ue2[2 * i + 1].x; sB.y = d[i].w + ue2[2 * i + 1].y;
                rB.x = frcp(1.0f + fexp2(sB.x));  rB.y = frcp(1.0f + fexp2(sB.y));
                accB += vd2[2 * i + 1] * rB;
            }
            f32x2 accT = accA + accB;
            float acc = accT.x + accT.y;
            acc += dppmov<0x111>(acc);      // odd lane holds full e[t]
            ex = fexp(acc + bvd0);
            if (q_e == 1) e_s[t_e] = ex;
        }
        __syncthreads();  // B3: e_s ready

        // phase f: softmax denom (DPP) + ctx partials from registers + ys
        {
            float ex0 = e_s[lane];
            float ex1 = e_s[64 + lane];
            float invS = frcp(rdlane(wavesum63(ex0 + ex1), 63));
            float exv = hv_sel ? ex0 : ex1;   // wave's 32 t's live in one half
            float p0 = 0.0f, p1 = 0.0f, p2 = 0.0f, p3 = 0.0f;
            #pragma unroll
            for (int j = 0; j < 8; j++) {
                p0 = fmaf(rdlane(exv, base32 + j),      enc_r[j],      p0);
                p1 = fmaf(rdlane(exv, base32 + 8 + j),  enc_r[8 + j],  p1);
                p2 = fmaf(rdlane(exv, base32 + 16 + j), enc_r[16 + j], p2);
                p3 = fmaf(rdlane(exv, base32 + 24 + j), enc_r[24 + j], p3);
            }
            float ctxv = ((p0 + p1) + (p2 + p3)) * invS;
            float yw = wavesum63(ctxv * Wde);
            if (lane == 63) ys_s[wv] = yw;
            if (st == Tn - 2) ctxp[wv * 64 + lane] = ctxv;
        }
        __syncthreads();  // B4: ys ready for next phase a
    }

    // ---- epilogue: out[b][p] = ((concat(h,ctx) @ Wvb + bvb) * Wb[p]) + bWb[p] ----
    if (wv == 0) {
        float ctxm = 0.0f;
        #pragma unroll
        for (int w = 0; w < NW; w++) ctxm += ctxp[w * 64 + lane];
        float part = h * Wvb[lane] + ctxm * Wvb[64 + lane];
        float v = rdlane(wavesum63(part), 63) + bvb[0];
        out[(size_t)b * Pn + lane] = fmaf(v, Wb[lane], bWb[lane]);
    }
}

extern "C" void kernel_launch(void* const* d_in, const int* in_sizes, int n_in,
                              void* d_out, int out_size, void* d_ws, size_t ws_size,
                              hipStream_t stream) {
    const float* data    = (const float*)d_in[0];
    const float* enc     = (const float*)d_in[1];
    const float* h0      = (const float*)d_in[2];
    const float* s0      = (const float*)d_in[3];
    const float* W_dense = (const float*)d_in[4];
    const float* b_dense = (const float*)d_in[5];
    const float* Wk      = (const float*)d_in[6];
    const float* Uk      = (const float*)d_in[7];
    const float* bk      = (const float*)d_in[8];
    const float* Wd      = (const float*)d_in[9];
    const float* bWd     = (const float*)d_in[10];
    const float* Ud      = (const float*)d_in[11];
    const float* bUd     = (const float*)d_in[12];
    const float* vd      = (const float*)d_in[13];
    const float* bvd     = (const float*)d_in[14];
    const float* Wvb     = (const float*)d_in[15];
    const float* bvb     = (const float*)d_in[16];
    const float* Wb      = (const float*)d_in[17];
    const float* bWb     = (const float*)d_in[18];

    decoder_kernel<<<Bn, NTH, SMEM_FLOATS * sizeof(float), stream>>>(
        data, enc, h0, s0, W_dense, b_dense, Wk, Uk, bk,
        Wd, bWd, Ud, bUd, vd, bvd, Wvb, bvb, Wb, bWb, (float*)d_out);
}

// Round 7
// 283.730 us; speedup vs baseline: 1.2860x; 1.1571x over previous
//
#include <hip/hip_runtime.h>

// Decoder scan: B=256 batch, T=128, M=64, P=64, 127 sequential steps.
// One block per batch element (256 blocks = 256 CUs), 256 threads (4 waves,
// 1 wave/SIMD). ONE barrier per step: every wave redundantly computes the
// LSTM gates AND the full dproj matvec (wd_r[128] in registers, readlane
// broadcast), bounces dproj through wave-PRIVATE LDS (no barrier), computes
// its own 32 attention scores, and publishes only 2 scalars (unscaled
// ctx.Wde numerator + softmax denominator) per step. Division deferred to
// the next step's phase a.

#define Bn 256
#define Tn 128
#define Mn 64
#define Pn 64
#define NTH 256
#define NW 4
#define UST 68   // padded stride (floats) for enc_s / Ud_s (init staging)
#define DPST 72  // padded stride for wave-private dproj copies
#define K2C 2.885390081777927f  // 2 * log2(e)

typedef float f32x2 __attribute__((ext_vector_type(2)));

__device__ __forceinline__ float fexp(float x) {   // e^x
    return __builtin_amdgcn_exp2f(x * 1.44269504088896341f);
}
__device__ __forceinline__ float fexp2(float x) { return __builtin_amdgcn_exp2f(x); }
__device__ __forceinline__ float frcp(float x) { return __builtin_amdgcn_rcpf(x); }
__device__ __forceinline__ float fsig(float x) { return frcp(1.0f + fexp(-x)); }
__device__ __forceinline__ float ftanh(float x) { return 1.0f - 2.0f * frcp(1.0f + fexp(2.0f * x)); }

template <int CTRL>
__device__ __forceinline__ float dppmov(float x) {
    // invalid source lanes contribute old=0 (safe for additive reductions)
    return __int_as_float(__builtin_amdgcn_update_dpp(
        0, __float_as_int(x), CTRL, 0xf, 0xf, false));
}
__device__ __forceinline__ float rdlane(float x, int l) {
    return __int_as_float(__builtin_amdgcn_readlane(__float_as_int(x), l));
}
// 64-lane sum; total lands in lane 63 (NOT broadcast)
__device__ __forceinline__ float wavesum63(float x) {
    x += dppmov<0x111>(x);  // row_shr:1
    x += dppmov<0x112>(x);  // row_shr:2
    x += dppmov<0x114>(x);  // row_shr:4
    x += dppmov<0x118>(x);  // row_shr:8
    x += dppmov<0x142>(x);  // row_bcast:15
    x += dppmov<0x143>(x);  // row_bcast:31
    return x;
}

// LDS layout (floats):
#define OFF_ENC   0        // 128*68 = 8704 (init only)
#define OFF_UD    8704     // 64*68  = 4352 (init only)
#define OFF_PRE   13056    // 256 (init only)
#define OFF_DPW   13312    // 4*72 = 288 (wave-private dproj copies)
#define OFF_YSDEN 13600    // f32x2[2][4] = 16 floats (8B aligned)
#define OFF_CTXP  13616    // 256
#define SMEM_FLOATS 13872  // 55.5 KB

__global__ __launch_bounds__(NTH, 1)
void decoder_kernel(const float* __restrict__ data, const float* __restrict__ enc,
                    const float* __restrict__ h0, const float* __restrict__ s0,
                    const float* __restrict__ W_dense, const float* __restrict__ b_dense,
                    const float* __restrict__ Wk, const float* __restrict__ Uk,
                    const float* __restrict__ bk,
                    const float* __restrict__ Wd, const float* __restrict__ bWd,
                    const float* __restrict__ Ud, const float* __restrict__ bUd,
                    const float* __restrict__ vd, const float* __restrict__ bvd,
                    const float* __restrict__ Wvb, const float* __restrict__ bvb,
                    const float* __restrict__ Wb, const float* __restrict__ bWb,
                    float* __restrict__ out)
{
    extern __shared__ float smem[];
    float* enc_s  = smem + OFF_ENC;
    float* Ud_s   = smem + OFF_UD;
    float* pre_s  = smem + OFF_PRE;
    float* dprojw = smem + OFF_DPW;
    f32x2* ysden  = (f32x2*)(smem + OFF_YSDEN);
    float* ctxp   = smem + OFF_CTXP;

    const int b    = blockIdx.x;
    const int tid  = threadIdx.x;
    const int lane = tid & 63;
    const int wv   = tid >> 6;          // 0..3

    // ---- init: stage enc (stride 68), Ud (stride 68); pre = h0@Uk+bk ----
    {
        const float* encg = enc + (size_t)b * Tn * Mn;
        #pragma unroll
        for (int i = 0; i < 8; i++) {
            int flat = (i * NTH + tid) * 4;          // 0..8188
            int t = flat >> 6, m = flat & 63;
            *(float4*)(enc_s + t * UST + m) = *(const float4*)(encg + flat);
        }
        #pragma unroll
        for (int i = 0; i < 4; i++) {
            int flat = (i * NTH + tid) * 4;          // 0..4092
            int k = flat >> 6, n = flat & 63;
            *(float4*)(Ud_s + k * UST + n) = *(const float4*)(Ud + flat);
        }
        {   // tid covers 0..255 == 4P exactly
            float s = bk[tid];
            const float* h0b = h0 + b * Pn;
            #pragma unroll
            for (int k = 0; k < Pn; k++) s = fmaf(h0b[k], Uk[k * 4 * Pn + tid], s);
            pre_s[tid] = s;
        }
        if (tid < 2 * NW) {                          // both parities
            f32x2 z; z.x = 0.0f; z.y = 0.25f;        // den sums to 1 -> ctx=0
            ysden[tid] = z;
        }
    }
    __syncthreads();

    // ---- Ue slice in registers: ue = K2*(enc[t] @ Ud[:, m0..m0+31] + bUd)
    //      t = 32*wv + (lane>>1), q = lane&1, m0 = 32q
    const int t_e = tid >> 1, q_e = tid & 1, m0 = q_e * 32;
    f32x2 ue2[16];
    {
        float acc[32];
        #pragma unroll
        for (int j = 0; j < 32; j++) acc[j] = bUd[m0 + j];
        for (int k = 0; k < Mn; k++) {
            float a = enc_s[t_e * UST + k];
            const float4* ud = (const float4*)(Ud_s + k * UST + m0);
            #pragma unroll
            for (int j4 = 0; j4 < 8; j4++) {
                float4 u = ud[j4];
                acc[4 * j4 + 0] = fmaf(a, u.x, acc[4 * j4 + 0]);
                acc[4 * j4 + 1] = fmaf(a, u.y, acc[4 * j4 + 1]);
                acc[4 * j4 + 2] = fmaf(a, u.z, acc[4 * j4 + 2]);
                acc[4 * j4 + 3] = fmaf(a, u.w, acc[4 * j4 + 3]);
            }
        }
        #pragma unroll
        for (int j = 0; j < 16; j++) {
            ue2[j].x = K2C * acc[2 * j];
            ue2[j].y = K2C * acc[2 * j + 1];
        }
    }

    // ---- per-lane loop-invariant registers ----
    float enc_r[32];                                   // wave's 32 enc rows
    #pragma unroll
    for (int j = 0; j < 32; j++)
        enc_r[j] = enc_s[(32 * wv + j) * UST + lane];
    float wd_r[128];                                   // FULL K2*Wd column m=lane
    #pragma unroll
    for (int k = 0; k < 128; k++)
        wd_r[k] = K2C * Wd[k * Mn + lane];
    const float W0  = W_dense[0];
    const float bd  = b_dense[0];
    const float Wde = W_dense[1 + lane];
    const float wk_i = Wk[lane], wk_f = Wk[64 + lane],
                wk_g = Wk[128 + lane], wk_o = Wk[192 + lane];
    const float s0v   = s0[b * Pn + lane];
    const float bvd0  = bvd[0];
    const float bwd_l = K2C * bWd[lane];
    f32x2 vd2[16];
    float sumvd32 = 0.0f;
    #pragma unroll
    for (int j = 0; j < 16; j++) {
        float va = vd[m0 + 2 * j], vb = vd[m0 + 2 * j + 1];
        vd2[j].x = -2.0f * va; vd2[j].y = -2.0f * vb;
        sumvd32 += va + vb;
    }
    const float pre_i = pre_s[lane];
    const float pre_f = pre_s[64 + lane];
    const float pre_g = pre_s[128 + lane];
    const float pre_o = pre_s[192 + lane];
    // x row in registers (broadcast later via v_readlane)
    const float* xb = data + (size_t)b * (Tn - 1);
    const float x_lo = xb[lane];                           // 0..63
    const float x_hi = (lane < 63) ? xb[64 + lane] : 0.0f; // 64..126

    float h = 0.0f, c = 0.0f;
    float* dp_my = dprojw + wv * DPST;                 // wave-private dproj

    for (int st = 0; st < Tn - 1; ++st) {
        const int par = st & 1, nxt = par ^ 1;

        // phase a: y = x[st]*W0 + (sum_w ysraw)/(sum_w den) + bd
        f32x2 yv = ysden[par * NW + (lane & 3)];
        yv.x += dppmov<0x111>(yv.x); yv.y += dppmov<0x111>(yv.y);
        yv.x += dppmov<0x112>(yv.x); yv.y += dppmov<0x112>(yv.y);
        float ytot = rdlane(yv.x, 3);
        float dtot = rdlane(yv.y, 3);
        float xs = (st < 64) ? rdlane(x_lo, st) : rdlane(x_hi, st - 64);
        float y = fmaf(xs, W0, fmaf(ytot, frcp(dtot), bd));

        // phase b: LSTM gates (state resets to h0,s0; pre = h0@Uk+bk)
        float zi = fmaf(y, wk_i, pre_i);
        float zf = fmaf(y, wk_f, pre_f);
        float zg = fmaf(y, wk_g, pre_g);
        float zo = fmaf(y, wk_o, pre_o);
        c = fsig(zf) * s0v + fsig(zi) * ftanh(zg);
        h = fsig(zo) * ftanh(c);

        // phase cd: FULL dproj[m=lane] per wave (redundant), no barrier.
        {
            float p0 = 0.0f, p1 = 0.0f, p2 = 0.0f, p3 = 0.0f;
            #pragma unroll
            for (int k = 0; k < 16; k++) {
                p0 = fmaf(rdlane(h, 4 * k + 0), wd_r[4 * k + 0], p0);
                p1 = fmaf(rdlane(h, 4 * k + 1), wd_r[4 * k + 1], p1);
                p2 = fmaf(rdlane(h, 4 * k + 2), wd_r[4 * k + 2], p2);
                p3 = fmaf(rdlane(h, 4 * k + 3), wd_r[4 * k + 3], p3);
            }
            #pragma unroll
            for (int k = 0; k < 16; k++) {
                p0 = fmaf(rdlane(c, 4 * k + 0), wd_r[64 + 4 * k + 0], p0);
                p1 = fmaf(rdlane(c, 4 * k + 1), wd_r[64 + 4 * k + 1], p1);
                p2 = fmaf(rdlane(c, 4 * k + 2), wd_r[64 + 4 * k + 2], p2);
                p3 = fmaf(rdlane(c, 4 * k + 3), wd_r[64 + 4 * k + 3], p3);
            }
            dp_my[lane] = ((p0 + p1) + (p2 + p3)) + bwd_l;  // pre-scaled K2
        }
        // in-wave LDS RAW: compiler inserts lgkmcnt wait; no cross-wave use.

        // phase e: e[t] = sum_m vd*tanh(dproj+Ue); ex=exp(e) at odd lanes
        float ex;
        {
            float4 d[8];
            const float4* dp4 = (const float4*)(dp_my + m0);
            #pragma unroll
            for (int i = 0; i < 8; i++) d[i] = dp4[i];
            f32x2 accA; accA.x = sumvd32; accA.y = 0.0f;
            f32x2 accB; accB.x = 0.0f;    accB.y = 0.0f;
            #pragma unroll
            for (int i = 0; i < 8; i++) {
                f32x2 sA, rA, sB, rB;
                sA.x = d[i].x + ue2[2 * i].x;     sA.y = d[i].y + ue2[2 * i].y;
                rA.x = frcp(1.0f + fexp2(sA.x));  rA.y = frcp(1.0f + fexp2(sA.y));
                accA += vd2[2 * i] * rA;
                sB.x = d[i].z + ue2[2 * i + 1].x; sB.y = d[i].w + ue2[2 * i + 1].y;
                rB.x = frcp(1.0f + fexp2(sB.x));  rB.y = frcp(1.0f + fexp2(sB.y));
                accB += vd2[2 * i + 1] * rB;
            }
            f32x2 accT = accA + accB;
            float acc = accT.x + accT.y;
            acc += dppmov<0x111>(acc);      // odd lane holds full e[t]
            ex = fexp(acc + bvd0);          // valid at odd lanes
        }

        // phase f: ctx partial (lane=m) from own-wave ex; publish 2 scalars
        {
            float p0 = 0.0f, p1 = 0.0f, p2 = 0.0f, p3 = 0.0f;
            #pragma unroll
            for (int j = 0; j < 8; j++) {
                p0 = fmaf(rdlane(ex, 2 * j + 1),        enc_r[j],      p0);
                p1 = fmaf(rdlane(ex, 2 * (j + 8) + 1),  enc_r[8 + j],  p1);
                p2 = fmaf(rdlane(ex, 2 * (j + 16) + 1), enc_r[16 + j], p2);
                p3 = fmaf(rdlane(ex, 2 * (j + 24) + 1), enc_r[24 + j], p3);
            }
            float ctxpart = (p0 + p1) + (p2 + p3);      // UNscaled
            if (st == Tn - 2) ctxp[wv * 64 + lane] = ctxpart;
            f32x2 w2;
            w2.x = ctxpart * Wde;
            w2.y = (lane & 1) ? ex : 0.0f;              // denom contribution
            w2.x += dppmov<0x111>(w2.x); w2.y += dppmov<0x111>(w2.y);
            w2.x += dppmov<0x112>(w2.x); w2.y += dppmov<0x112>(w2.y);
            w2.x += dppmov<0x114>(w2.x); w2.y += dppmov<0x114>(w2.y);
            w2.x += dppmov<0x118>(w2.x); w2.y += dppmov<0x118>(w2.y);
            w2.x += dppmov<0x142>(w2.x); w2.y += dppmov<0x142>(w2.y);
            w2.x += dppmov<0x143>(w2.x); w2.y += dppmov<0x143>(w2.y);
            if (lane == 63) ysden[nxt * NW + wv] = w2;
        }
        __syncthreads();  // the ONE barrier: ysden (and last-step ctxp) ready
    }

    // ---- epilogue: out[b][p] = ((concat(h,ctx) @ Wvb + bvb) * Wb[p]) + bWb[p]
    //      last step (st=126, par=0) wrote ysden[1][*]; ctxp holds unscaled.
    if (wv == 0) {
        float dtot = ysden[NW + 0].y + ysden[NW + 1].y
                   + ysden[NW + 2].y + ysden[NW + 3].y;
        float invS = frcp(dtot);
        float ctxm = 0.0f;
        #pragma unroll
        for (int w = 0; w < NW; w++) ctxm += ctxp[w * 64 + lane];
        ctxm *= invS;
        float part = h * Wvb[lane] + ctxm * Wvb[64 + lane];
        float v = rdlane(wavesum63(part), 63) + bvb[0];
        out[(size_t)b * Pn + lane] = fmaf(v, Wb[lane], bWb[lane]);
    }
}

extern "C" void kernel_launch(void* const* d_in, const int* in_sizes, int n_in,
                              void* d_out, int out_size, void* d_ws, size_t ws_size,
                              hipStream_t stream) {
    const float* data    = (const float*)d_in[0];
    const float* enc     = (const float*)d_in[1];
    const float* h0      = (const float*)d_in[2];
    const float* s0      = (const float*)d_in[3];
    const float* W_dense = (const float*)d_in[4];
    const float* b_dense = (const float*)d_in[5];
    const float* Wk      = (const float*)d_in[6];
    const float* Uk      = (const float*)d_in[7];
    const float* bk      = (const float*)d_in[8];
    const float* Wd      = (const float*)d_in[9];
    const float* bWd     = (const float*)d_in[10];
    const float* Ud      = (const float*)d_in[11];
    const float* bUd     = (const float*)d_in[12];
    const float* vd      = (const float*)d_in[13];
    const float* bvd     = (const float*)d_in[14];
    const float* Wvb     = (const float*)d_in[15];
    const float* bvb     = (const float*)d_in[16];
    const float* Wb      = (const float*)d_in[17];
    const float* bWb     = (const float*)d_in[18];

    decoder_kernel<<<Bn, NTH, SMEM_FLOATS * sizeof(float), stream>>>(
        data, enc, h0, s0, W_dense, b_dense, Wk, Uk, bk,
        Wd, bWd, Ud, bUd, vd, bvd, Wvb, bvb, Wb, bWb, (float*)d_out);
}